// Round 1
// baseline (1534.304 us; speedup 1.0000x reference)
//
#include <hip/hip_runtime.h>

// ---------------------------------------------------------------------------
// Decoder layer (B=4, S=2048, D=1024, H=16, Dh=64, FF=4096), f32 in/out.
// Internally: f16 MFMA GEMMs (f32 accum), f32 softmax/LN.
// Round 0: correctness-first. Materialized attention scores in a static arena.
// ---------------------------------------------------------------------------

typedef _Float16 f16;
typedef _Float16 f16x8 __attribute__((ext_vector_type(8)));
typedef _Float16 f16x4 __attribute__((ext_vector_type(4)));
typedef float f32x4 __attribute__((ext_vector_type(4)));

constexpr int S_LEN = 2048;
constexpr int NB    = 4;
constexpr int DM    = 1024;
constexpr int M_TOK = NB * S_LEN;          // 8192 tokens

// ---- static device arena (byte offsets) ----
constexpr long OFF_W   = 0;                // 16M f16 = 32 MiB (transposed weights)
constexpr long OFF_XB  = 32L  << 20;       // current stream, f16 [8192,1024]
constexpr long OFF_ENC = 48L  << 20;       // encoder f16
constexpr long OFF_Q   = 64L  << 20;
constexpr long OFF_K   = 80L  << 20;
constexpr long OFF_V   = 96L  << 20;
constexpr long OFF_VT  = 112L << 20;       // V transposed per head [bh][64][S]
constexpr long OFF_AC  = 128L << 20;       // attention concat f16
constexpr long OFF_HID = 144L << 20;       // FF hidden f16 [8192,4096] (64 MiB)
constexpr long OFF_F1  = 208L << 20;       // f32 [8192,1024]
constexpr long OFF_F2  = 240L << 20;       // f32
constexpr long OFF_F3  = 272L << 20;       // f32
constexpr long OFF_SC  = 304L << 20;       // scores f16 [64][2048][2048] (512 MiB)
constexpr long BUF_BYTES = 816L << 20;

__device__ alignas(4096) unsigned char g_buf[BUF_BYTES];

// transposed-weight element offsets (bytes)
constexpr long WQ1T = OFF_W + (0L  << 20);
constexpr long WK1T = OFF_W + (2L  << 20);
constexpr long WV1T = OFF_W + (4L  << 20);
constexpr long WO1T = OFF_W + (6L  << 20);
constexpr long WQ2T = OFF_W + (8L  << 20);
constexpr long WK2T = OFF_W + (10L << 20);
constexpr long WV2T = OFF_W + (12L << 20);
constexpr long WO2T = OFF_W + (14L << 20);
constexpr long WF1T = OFF_W + (16L << 20);  // [4096][1024]
constexpr long WF2T = OFF_W + (24L << 20);  // [1024][4096]

// ---------------------------------------------------------------------------
// f32 -> f16 convert (vectorized, exact grid)
// ---------------------------------------------------------------------------
__global__ __launch_bounds__(256) void cvt_f32_f16_k(const float* __restrict__ in, long outOff)
{
    f16* out = (f16*)(g_buf + outOff);
    long i = (long)blockIdx.x * 256 + threadIdx.x;
    float4 v = ((const float4*)in)[i];
    f16x4 h;
    h.x = (f16)v.x; h.y = (f16)v.y; h.z = (f16)v.z; h.w = (f16)v.w;
    *(f16x4*)(out + i * 4) = h;
}

// ---------------------------------------------------------------------------
// weight transpose + convert: W f32 [K,N] -> Wt f16 [N,K]
// ---------------------------------------------------------------------------
__global__ __launch_bounds__(256) void transw_k(const float* __restrict__ W, long outOff, int K, int N)
{
    __shared__ float t[32][33];
    f16* Wt = (f16*)(g_buf + outOff);
    int tx = threadIdx.x, ty = threadIdx.y;
    int c0 = blockIdx.x * 32, r0 = blockIdx.y * 32;
#pragma unroll
    for (int i = 0; i < 4; ++i)
        t[ty + 8*i][tx] = W[(long)(r0 + ty + 8*i) * N + c0 + tx];
    __syncthreads();
#pragma unroll
    for (int i = 0; i < 4; ++i)
        Wt[(long)(c0 + ty + 8*i) * K + r0 + tx] = (f16)t[tx][ty + 8*i];
}

// ---------------------------------------------------------------------------
// per-head V transpose: V f16 [b*S+s][h*64+d] -> Vt f16 [bh][d][s]
// ---------------------------------------------------------------------------
__global__ __launch_bounds__(256) void transv_k(long vOff, long vtOff)
{
    __shared__ f16 t[32][33];
    const f16* V = (const f16*)(g_buf + vOff);
    f16* Vt = (f16*)(g_buf + vtOff);
    int tx = threadIdx.x, ty = threadIdx.y;
    int bh = blockIdx.z; int b = bh >> 4, h = bh & 15;
    int s0 = blockIdx.x * 32, d0 = blockIdx.y * 32;
#pragma unroll
    for (int i = 0; i < 4; ++i)
        t[ty + 8*i][tx] = V[(long)(b * S_LEN + s0 + ty + 8*i) * DM + h * 64 + d0 + tx];
    __syncthreads();
#pragma unroll
    for (int i = 0; i < 4; ++i)
        Vt[((long)bh * 64 + d0 + ty + 8*i) * S_LEN + s0 + tx] = t[tx][ty + 8*i];
}

// ---------------------------------------------------------------------------
// GEMM: C[M,N] = A[M,K] @ B^T-layout[N,K] (+bias/relu/scale/mask)
// MODE 0: f16 out + bias        MODE 1: f16 out + bias + relu
// MODE 2: f32 out + bias        MODE 3: f16 out, *scale, causal mask
// MODE 4: f16 out, *scale       MODE 5: f16 out plain
// 128xBN tile, BK=32, 4 waves (2x2), m97-class structure.
// ---------------------------------------------------------------------------
template<int BM, int BN, int MODE>
__global__ __launch_bounds__(256) void gemm_k(
    long aOff, long bOff, long cOff, const float* __restrict__ bias,
    int K, int lda, int ldb, int ldc,
    long aS1, long aS2, long bS1, long bS2, long cS1, long cS2,
    int zInner, float scale, int kLimitCausal)
{
    constexpr int FM = BM / 32;
    constexpr int FN = BN / 32;
    __shared__ f16 As[BM * 32];
    __shared__ f16 Bs[BN * 32];

    const int tid  = threadIdx.x;
    const int lane = tid & 63;
    const int wid  = tid >> 6;
    const int row0 = blockIdx.y * BM;
    const int col0 = blockIdx.x * BN;
    const int z  = blockIdx.z;
    const int zb = z / zInner, zh = z % zInner;

    if constexpr (MODE == 3) {
        // block fully above the diagonal: never read downstream -> skip it all
        if (col0 > row0 + BM - 1) return;
    }

    const f16* Ab = (const f16*)(g_buf + aOff) + zb * aS1 + zh * aS2;
    const f16* Bb = (const f16*)(g_buf + bOff) + zb * bS1 + zh * bS2;
    const long cBase = zb * cS1 + zh * cS2;

    const int wr = (wid >> 1) * (BM / 2);
    const int wc = (wid & 1)  * (BN / 2);
    const int rB = (lane >> 4) * 4;
    const int cB = lane & 15;
    const int kg = (lane >> 4) * 8;

    f32x4 acc[FM][FN] = {};

    const int kIters = kLimitCausal ? (row0 + BM) / 32 : K / 32;
    for (int kt = 0; kt < kIters; ++kt) {
        const int kBase = kt * 32;
        // stage A tile [BM][32] via global_load_lds (linear LDS, per-lane src)
#pragma unroll
        for (int t = 0; t < BM / 64; ++t) {
            int i = wid + t * 4;
            const f16* gp = Ab + (long)(row0 + i * 16 + (lane >> 2)) * lda + kBase + (lane & 3) * 8;
            __builtin_amdgcn_global_load_lds((const __attribute__((address_space(1))) void*)gp,
                (__attribute__((address_space(3))) void*)(As + i * 512), 16, 0, 0);
        }
        // stage B tile [BN][32]
#pragma unroll
        for (int t = 0; t < BN / 64; ++t) {
            int i = wid + t * 4;
            const f16* gp = Bb + (long)(col0 + i * 16 + (lane >> 2)) * ldb + kBase + (lane & 3) * 8;
            __builtin_amdgcn_global_load_lds((const __attribute__((address_space(1))) void*)gp,
                (__attribute__((address_space(3))) void*)(Bs + i * 512), 16, 0, 0);
        }
        __syncthreads();

        f16x8 af[FM], bf[FN];
#pragma unroll
        for (int m = 0; m < FM; ++m)
            af[m] = *(const f16x8*)&As[(wr + m * 16 + cB) * 32 + kg];
#pragma unroll
        for (int n = 0; n < FN; ++n)
            bf[n] = *(const f16x8*)&Bs[(wc + n * 16 + cB) * 32 + kg];
#pragma unroll
        for (int m = 0; m < FM; ++m)
#pragma unroll
            for (int n = 0; n < FN; ++n)
                acc[m][n] = __builtin_amdgcn_mfma_f32_16x16x32_f16(af[m], bf[n], acc[m][n], 0, 0, 0);
        __syncthreads();
    }

    // epilogue
    float* Cf = (float*)(g_buf + cOff);
    f16*  Ch = (f16*)(g_buf + cOff);
#pragma unroll
    for (int m = 0; m < FM; ++m) {
#pragma unroll
        for (int n = 0; n < FN; ++n) {
            const int c = col0 + wc + n * 16 + cB;
            float bv = 0.f;
            if constexpr (MODE <= 2) bv = bias[c];
#pragma unroll
            for (int j = 0; j < 4; ++j) {
                const int r = row0 + wr + m * 16 + rB + j;
                float v = acc[m][n][j] + bv;
                if constexpr (MODE == 1) v = fmaxf(v, 0.f);
                if constexpr (MODE == 3 || MODE == 4) v *= scale;
                if constexpr (MODE == 3) { if (c > r) v = -__builtin_inff(); }
                const long idx = cBase + (long)r * ldc + c;
                if constexpr (MODE == 2) Cf[idx] = v;
                else                     Ch[idx] = (f16)v;
            }
        }
    }
}

// ---------------------------------------------------------------------------
// row softmax over S=2048, in place on f16 scores. One wave per row.
// causal: mask by column index (garbage beyond diagonal is never trusted),
// and only touch chunks up to the 128-aligned row limit (PV reads that far).
// ---------------------------------------------------------------------------
__global__ __launch_bounds__(256) void softmax_k(long scOff, int causal)
{
    f16* sc = (f16*)(g_buf + scOff);
    const int lane = threadIdx.x & 63;
    const long row = (long)blockIdx.x * 4 + (threadIdx.x >> 6);
    f16* rp = sc + row * S_LEN;

    const int q   = causal ? (int)(row & (S_LEN - 1)) : S_LEN;
    const int nch = causal ? (((((q >> 7) + 1) << 7) + 511) >> 9) : 4;
    const float NEG = -__builtin_inff();

    float v[32];
#pragma unroll
    for (int c = 0; c < 4; ++c) {
        if (c < nch) {
            f16x8 h = *(const f16x8*)(rp + c * 512 + lane * 8);
#pragma unroll
            for (int j = 0; j < 8; ++j) {
                int kk = c * 512 + lane * 8 + j;
                v[c * 8 + j] = (kk > q) ? NEG : (float)h[j];
            }
        } else {
#pragma unroll
            for (int j = 0; j < 8; ++j) v[c * 8 + j] = NEG;
        }
    }
    float m = NEG;
#pragma unroll
    for (int i = 0; i < 32; ++i) m = fmaxf(m, v[i]);
#pragma unroll
    for (int o = 32; o > 0; o >>= 1) m = fmaxf(m, __shfl_xor(m, o));
    float s = 0.f;
#pragma unroll
    for (int i = 0; i < 32; ++i) { v[i] = __expf(v[i] - m); s += v[i]; }
#pragma unroll
    for (int o = 32; o > 0; o >>= 1) s += __shfl_xor(s, o);
    const float rinv = 1.0f / s;
#pragma unroll
    for (int c = 0; c < 4; ++c) {
        if (c < nch) {
            f16x8 h;
#pragma unroll
            for (int j = 0; j < 8; ++j) h[j] = (f16)(v[c * 8 + j] * rinv);
            *(f16x8*)(rp + c * 512 + lane * 8) = h;
        }
    }
}

// ---------------------------------------------------------------------------
// fused residual-add + LayerNorm. One block (256 thr) per row of 1024.
// Writes f32 (internal or d_out) and f16 (next GEMM input).
// ---------------------------------------------------------------------------
__global__ __launch_bounds__(256) void ln_k(
    long inOff, const float* __restrict__ residExt, long residOff,
    const float* __restrict__ gamma, const float* __restrict__ beta,
    float* __restrict__ outFExt, long outFOff, long outHOff)
{
    const float* in    = (const float*)(g_buf + inOff);
    const float* resid = residExt ? residExt : (const float*)(g_buf + residOff);
    float* outF = outFExt ? outFExt : (float*)(g_buf + outFOff);
    f16*  outH = (f16*)(g_buf + outHOff);

    const long row = blockIdx.x;
    const int tid = threadIdx.x;
    const int lane = tid & 63, wid = tid >> 6;

    float4 a  = ((const float4*)(in    + row * DM))[tid];
    float4 rr = ((const float4*)(resid + row * DM))[tid];
    float x0 = a.x + rr.x, x1 = a.y + rr.y, x2 = a.z + rr.z, x3 = a.w + rr.w;

    __shared__ float red[4];
    float s = x0 + x1 + x2 + x3;
#pragma unroll
    for (int o = 32; o > 0; o >>= 1) s += __shfl_xor(s, o);
    if (lane == 0) red[wid] = s;
    __syncthreads();
    const float mu = (red[0] + red[1] + red[2] + red[3]) * (1.0f / DM);

    float d0 = x0 - mu, d1 = x1 - mu, d2 = x2 - mu, d3 = x3 - mu;
    float qq = d0*d0 + d1*d1 + d2*d2 + d3*d3;
#pragma unroll
    for (int o = 32; o > 0; o >>= 1) qq += __shfl_xor(qq, o);
    __syncthreads();
    if (lane == 0) red[wid] = qq;
    __syncthreads();
    const float var = (red[0] + red[1] + red[2] + red[3]) * (1.0f / DM);
    const float rs = rsqrtf(var + 1e-6f);

    float4 g  = ((const float4*)gamma)[tid];
    float4 be = ((const float4*)beta)[tid];
    float y0 = d0 * rs * g.x + be.x;
    float y1 = d1 * rs * g.y + be.y;
    float y2 = d2 * rs * g.z + be.z;
    float y3 = d3 * rs * g.w + be.w;

    ((float4*)(outF + row * DM))[tid] = make_float4(y0, y1, y2, y3);
    f16x4 h; h.x = (f16)y0; h.y = (f16)y1; h.z = (f16)y2; h.w = (f16)y3;
    *(f16x4*)(outH + row * DM + tid * 4) = h;
}

// ---------------------------------------------------------------------------
extern "C" void kernel_launch(void* const* d_in, const int* in_sizes, int n_in,
                              void* d_out, int out_size, void* d_ws, size_t ws_size,
                              hipStream_t stream)
{
    (void)in_sizes; (void)n_in; (void)d_ws; (void)ws_size; (void)out_size;
    const float* x   = (const float*)d_in[0];
    const float* enc = (const float*)d_in[1];
    const float* wq1 = (const float*)d_in[2];  const float* bq1 = (const float*)d_in[3];
    const float* wk1 = (const float*)d_in[4];  const float* bk1 = (const float*)d_in[5];
    const float* wv1 = (const float*)d_in[6];  const float* bv1 = (const float*)d_in[7];
    const float* wo1 = (const float*)d_in[8];  const float* bo1 = (const float*)d_in[9];
    const float* wq2 = (const float*)d_in[10]; const float* bq2 = (const float*)d_in[11];
    const float* wk2 = (const float*)d_in[12]; const float* bk2 = (const float*)d_in[13];
    const float* wv2 = (const float*)d_in[14]; const float* bv2 = (const float*)d_in[15];
    const float* wo2 = (const float*)d_in[16]; const float* bo2 = (const float*)d_in[17];
    const float* wf1 = (const float*)d_in[18]; const float* bf1 = (const float*)d_in[19];
    const float* wf2 = (const float*)d_in[20]; const float* bf2 = (const float*)d_in[21];
    const float* g1  = (const float*)d_in[22]; const float* be1 = (const float*)d_in[23];
    const float* g2  = (const float*)d_in[24]; const float* be2 = (const float*)d_in[25];
    const float* g3  = (const float*)d_in[26]; const float* be3 = (const float*)d_in[27];
    float* out = (float*)d_out;

    const dim3 T256(256), T32x8(32, 8);
    const long SS = (long)S_LEN * S_LEN;      // 4.19M (per-head score matrix)
    const long SD = (long)S_LEN * DM;         // per-batch token stride

    // ---- converts & weight transposes ----
    cvt_f32_f16_k<<<8192, T256, 0, stream>>>(x,   OFF_XB);
    cvt_f32_f16_k<<<8192, T256, 0, stream>>>(enc, OFF_ENC);
    transw_k<<<dim3(32, 32),  T32x8, 0, stream>>>(wq1, WQ1T, 1024, 1024);
    transw_k<<<dim3(32, 32),  T32x8, 0, stream>>>(wk1, WK1T, 1024, 1024);
    transw_k<<<dim3(32, 32),  T32x8, 0, stream>>>(wv1, WV1T, 1024, 1024);
    transw_k<<<dim3(32, 32),  T32x8, 0, stream>>>(wo1, WO1T, 1024, 1024);
    transw_k<<<dim3(32, 32),  T32x8, 0, stream>>>(wq2, WQ2T, 1024, 1024);
    transw_k<<<dim3(32, 32),  T32x8, 0, stream>>>(wk2, WK2T, 1024, 1024);
    transw_k<<<dim3(32, 32),  T32x8, 0, stream>>>(wv2, WV2T, 1024, 1024);
    transw_k<<<dim3(32, 32),  T32x8, 0, stream>>>(wo2, WO2T, 1024, 1024);
    transw_k<<<dim3(128, 32), T32x8, 0, stream>>>(wf1, WF1T, 1024, 4096);
    transw_k<<<dim3(32, 128), T32x8, 0, stream>>>(wf2, WF2T, 4096, 1024);

    // ---- masked self-attention ----
    gemm_k<128,128,0><<<dim3(8,64,1), T256, 0, stream>>>(OFF_XB, WQ1T, OFF_Q, bq1,
        1024, 1024,1024,1024, 0,0,0,0,0,0, 1, 1.f, 0);
    gemm_k<128,128,0><<<dim3(8,64,1), T256, 0, stream>>>(OFF_XB, WK1T, OFF_K, bk1,
        1024, 1024,1024,1024, 0,0,0,0,0,0, 1, 1.f, 0);
    gemm_k<128,128,0><<<dim3(8,64,1), T256, 0, stream>>>(OFF_XB, WV1T, OFF_V, bv1,
        1024, 1024,1024,1024, 0,0,0,0,0,0, 1, 1.f, 0);
    transv_k<<<dim3(64,2,64), T32x8, 0, stream>>>(OFF_V, OFF_VT);
    gemm_k<128,128,3><<<dim3(16,16,64), T256, 0, stream>>>(OFF_Q, OFF_K, OFF_SC, nullptr,
        64, 1024,1024,2048, SD,64, SD,64, 16*SS, SS, 16, 0.125f, 0);
    softmax_k<<<32768, T256, 0, stream>>>(OFF_SC, 1);
    gemm_k<128,64,5><<<dim3(1,16,64), T256, 0, stream>>>(OFF_SC, OFF_VT, OFF_AC, nullptr,
        2048, 2048,2048,1024, 16*SS, SS, 1024L*S_LEN, 64L*S_LEN, SD, 64, 16, 1.f, 1);
    gemm_k<128,128,2><<<dim3(8,64,1), T256, 0, stream>>>(OFF_AC, WO1T, OFF_F2, bo1,
        1024, 1024,1024,1024, 0,0,0,0,0,0, 1, 1.f, 0);
    ln_k<<<8192, T256, 0, stream>>>(OFF_F2, x, 0, g1, be1, nullptr, OFF_F1, OFF_XB);

    // ---- cross-attention (q=enc, k=enc, v=x1) ----
    gemm_k<128,128,0><<<dim3(8,64,1), T256, 0, stream>>>(OFF_ENC, WQ2T, OFF_Q, bq2,
        1024, 1024,1024,1024, 0,0,0,0,0,0, 1, 1.f, 0);
    gemm_k<128,128,0><<<dim3(8,64,1), T256, 0, stream>>>(OFF_ENC, WK2T, OFF_K, bk2,
        1024, 1024,1024,1024, 0,0,0,0,0,0, 1, 1.f, 0);
    gemm_k<128,128,0><<<dim3(8,64,1), T256, 0, stream>>>(OFF_XB, WV2T, OFF_V, bv2,
        1024, 1024,1024,1024, 0,0,0,0,0,0, 1, 1.f, 0);
    transv_k<<<dim3(64,2,64), T32x8, 0, stream>>>(OFF_V, OFF_VT);
    gemm_k<128,128,4><<<dim3(16,16,64), T256, 0, stream>>>(OFF_Q, OFF_K, OFF_SC, nullptr,
        64, 1024,1024,2048, SD,64, SD,64, 16*SS, SS, 16, 0.125f, 0);
    softmax_k<<<32768, T256, 0, stream>>>(OFF_SC, 0);
    gemm_k<128,64,5><<<dim3(1,16,64), T256, 0, stream>>>(OFF_SC, OFF_VT, OFF_AC, nullptr,
        2048, 2048,2048,1024, 16*SS, SS, 1024L*S_LEN, 64L*S_LEN, SD, 64, 16, 1.f, 0);
    gemm_k<128,128,2><<<dim3(8,64,1), T256, 0, stream>>>(OFF_AC, WO2T, OFF_F2, bo2,
        1024, 1024,1024,1024, 0,0,0,0,0,0, 1, 1.f, 0);
    ln_k<<<8192, T256, 0, stream>>>(OFF_F2, nullptr, OFF_F1, g2, be2, nullptr, OFF_F3, OFF_XB);

    // ---- feed-forward ----
    gemm_k<128,128,1><<<dim3(32,64,1), T256, 0, stream>>>(OFF_XB, WF1T, OFF_HID, bf1,
        1024, 1024,1024,4096, 0,0,0,0,0,0, 1, 1.f, 0);
    gemm_k<128,128,2><<<dim3(8,64,1), T256, 0, stream>>>(OFF_HID, WF2T, OFF_F2, bf2,
        4096, 4096,4096,1024, 0,0,0,0,0,0, 1, 1.f, 0);
    ln_k<<<8192, T256, 0, stream>>>(OFF_F2, nullptr, OFF_F3, g3, be3, out, 0, OFF_XB);
}

// Round 2
// 1058.645 us; speedup vs baseline: 1.4493x; 1.4493x over previous
//
#include <hip/hip_runtime.h>

// ---------------------------------------------------------------------------
// Decoder layer (B=4, S=2048, D=1024, H=16, Dh=64, FF=4096), f32 in/out.
// Internally: f16 MFMA GEMMs (f32 accum), f32 softmax/LN.
// Round 1: fused flash attention (no materialized scores).
// ---------------------------------------------------------------------------

typedef _Float16 f16;
typedef _Float16 f16x8 __attribute__((ext_vector_type(8)));
typedef _Float16 f16x4 __attribute__((ext_vector_type(4)));
typedef float f32x4 __attribute__((ext_vector_type(4)));

constexpr int S_LEN = 2048;
constexpr int NB    = 4;
constexpr int DM    = 1024;

// ---- static device arena (byte offsets) ----
constexpr long OFF_W   = 0;                // transposed weights f16 (32 MiB)
constexpr long OFF_XB  = 32L  << 20;       // current stream, f16 [8192,1024]
constexpr long OFF_ENC = 48L  << 20;       // encoder f16
constexpr long OFF_Q   = 64L  << 20;
constexpr long OFF_K   = 80L  << 20;
constexpr long OFF_V   = 96L  << 20;
constexpr long OFF_VT  = 112L << 20;       // V transposed per head [bh][64][S]
constexpr long OFF_AC  = 128L << 20;       // attention concat f16
constexpr long OFF_HID = 144L << 20;       // FF hidden f16 [8192,4096]
constexpr long OFF_F1  = 208L << 20;       // f32 [8192,1024]
constexpr long OFF_F2  = 240L << 20;       // f32
constexpr long OFF_F3  = 272L << 20;       // f32
constexpr long BUF_BYTES = 304L << 20;

__device__ alignas(4096) unsigned char g_buf[BUF_BYTES];

constexpr long WQ1T = OFF_W + (0L  << 20);
constexpr long WK1T = OFF_W + (2L  << 20);
constexpr long WV1T = OFF_W + (4L  << 20);
constexpr long WO1T = OFF_W + (6L  << 20);
constexpr long WQ2T = OFF_W + (8L  << 20);
constexpr long WK2T = OFF_W + (10L << 20);
constexpr long WV2T = OFF_W + (12L << 20);
constexpr long WO2T = OFF_W + (14L << 20);
constexpr long WF1T = OFF_W + (16L << 20);  // [4096][1024]
constexpr long WF2T = OFF_W + (24L << 20);  // [1024][4096]

// ---------------------------------------------------------------------------
__global__ __launch_bounds__(256) void cvt_f32_f16_k(const float* __restrict__ in, long outOff)
{
    f16* out = (f16*)(g_buf + outOff);
    long i = (long)blockIdx.x * 256 + threadIdx.x;
    float4 v = ((const float4*)in)[i];
    f16x4 h;
    h.x = (f16)v.x; h.y = (f16)v.y; h.z = (f16)v.z; h.w = (f16)v.w;
    *(f16x4*)(out + i * 4) = h;
}

// weight transpose + convert: W f32 [K,N] -> Wt f16 [N,K]
__global__ __launch_bounds__(256) void transw_k(const float* __restrict__ W, long outOff, int K, int N)
{
    __shared__ float t[32][33];
    f16* Wt = (f16*)(g_buf + outOff);
    int tx = threadIdx.x, ty = threadIdx.y;
    int c0 = blockIdx.x * 32, r0 = blockIdx.y * 32;
#pragma unroll
    for (int i = 0; i < 4; ++i)
        t[ty + 8*i][tx] = W[(long)(r0 + ty + 8*i) * N + c0 + tx];
    __syncthreads();
#pragma unroll
    for (int i = 0; i < 4; ++i)
        Wt[(long)(c0 + ty + 8*i) * K + r0 + tx] = (f16)t[tx][ty + 8*i];
}

// per-head V transpose: V f16 [b*S+s][h*64+d] -> Vt f16 [bh][d][s]
__global__ __launch_bounds__(256) void transv_k(long vOff, long vtOff)
{
    __shared__ f16 t[32][33];
    const f16* V = (const f16*)(g_buf + vOff);
    f16* Vt = (f16*)(g_buf + vtOff);
    int tx = threadIdx.x, ty = threadIdx.y;
    int bh = blockIdx.z; int b = bh >> 4, h = bh & 15;
    int s0 = blockIdx.x * 32, d0 = blockIdx.y * 32;
#pragma unroll
    for (int i = 0; i < 4; ++i)
        t[ty + 8*i][tx] = V[(long)(b * S_LEN + s0 + ty + 8*i) * DM + h * 64 + d0 + tx];
    __syncthreads();
#pragma unroll
    for (int i = 0; i < 4; ++i)
        Vt[((long)bh * 64 + d0 + ty + 8*i) * S_LEN + s0 + tx] = t[tx][ty + 8*i];
}

// ---------------------------------------------------------------------------
// GEMM: C[M,N] = A[M,K] @ Bt[N,K] (+bias / relu)
// MODE 0: f16 out + bias   MODE 1: f16 out + bias + relu   MODE 2: f32 out + bias
// ---------------------------------------------------------------------------
template<int BM, int BN, int MODE>
__global__ __launch_bounds__(256) void gemm_k(
    long aOff, long bOff, long cOff, const float* __restrict__ bias,
    int K, int lda, int ldb, int ldc)
{
    constexpr int FM = BM / 32;
    constexpr int FN = BN / 32;
    __shared__ f16 As[BM * 32];
    __shared__ f16 Bs[BN * 32];

    const int tid  = threadIdx.x;
    const int lane = tid & 63;
    const int wid  = tid >> 6;
    const int row0 = blockIdx.y * BM;
    const int col0 = blockIdx.x * BN;

    const f16* Ab = (const f16*)(g_buf + aOff);
    const f16* Bb = (const f16*)(g_buf + bOff);

    const int wr = (wid >> 1) * (BM / 2);
    const int wc = (wid & 1)  * (BN / 2);
    const int rB = (lane >> 4) * 4;
    const int cB = lane & 15;
    const int kg = (lane >> 4) * 8;

    f32x4 acc[FM][FN] = {};

    for (int kt = 0; kt < K / 32; ++kt) {
        const int kBase = kt * 32;
#pragma unroll
        for (int t = 0; t < BM / 64; ++t) {
            int i = wid + t * 4;
            const f16* gp = Ab + (long)(row0 + i * 16 + (lane >> 2)) * lda + kBase + (lane & 3) * 8;
            __builtin_amdgcn_global_load_lds((const __attribute__((address_space(1))) void*)gp,
                (__attribute__((address_space(3))) void*)(As + i * 512), 16, 0, 0);
        }
#pragma unroll
        for (int t = 0; t < BN / 64; ++t) {
            int i = wid + t * 4;
            const f16* gp = Bb + (long)(col0 + i * 16 + (lane >> 2)) * ldb + kBase + (lane & 3) * 8;
            __builtin_amdgcn_global_load_lds((const __attribute__((address_space(1))) void*)gp,
                (__attribute__((address_space(3))) void*)(Bs + i * 512), 16, 0, 0);
        }
        __syncthreads();

        f16x8 af[FM], bf[FN];
#pragma unroll
        for (int m = 0; m < FM; ++m)
            af[m] = *(const f16x8*)&As[(wr + m * 16 + cB) * 32 + kg];
#pragma unroll
        for (int n = 0; n < FN; ++n)
            bf[n] = *(const f16x8*)&Bs[(wc + n * 16 + cB) * 32 + kg];
#pragma unroll
        for (int m = 0; m < FM; ++m)
#pragma unroll
            for (int n = 0; n < FN; ++n)
                acc[m][n] = __builtin_amdgcn_mfma_f32_16x16x32_f16(af[m], bf[n], acc[m][n], 0, 0, 0);
        __syncthreads();
    }

    float* Cf = (float*)(g_buf + cOff);
    f16*  Ch = (f16*)(g_buf + cOff);
#pragma unroll
    for (int m = 0; m < FM; ++m) {
#pragma unroll
        for (int n = 0; n < FN; ++n) {
            const int c = col0 + wc + n * 16 + cB;
            const float bv = bias[c];
#pragma unroll
            for (int j = 0; j < 4; ++j) {
                const int r = row0 + wr + m * 16 + rB + j;
                float v = acc[m][n][j] + bv;
                if constexpr (MODE == 1) v = fmaxf(v, 0.f);
                const long idx = (long)r * ldc + c;
                if constexpr (MODE == 2) Cf[idx] = v;
                else                     Ch[idx] = (f16)v;
            }
        }
    }
}

// ---------------------------------------------------------------------------
// Fused flash attention.
// Block = 128 q rows of one (b,h); 4 waves x 32 rows. KV chunk = 64.
// Q,K: f16 [b*S+s][h*64+d]; Vt: f16 [bh][d][s]; O: f16 [b*S+s][h*64+d].
// K/V LDS tiles staged via global_load_lds with pre-swizzled source
// (16B block index ^ (row&7)) -> conflict-free ds_read_b128 fragments.
// P round-trips through per-wave LDS (row pad 72 f16, keeps 16B alignment).
// ---------------------------------------------------------------------------
template<int CAUSAL>
__global__ __launch_bounds__(256) void flash_k(long qOff, long kOff, long vtOff, long oOff)
{
    __shared__ f16 Ks[64 * 64];
    __shared__ f16 Vs[64 * 64];
    __shared__ f16 Ps[4][32 * 72];

    const int tid  = threadIdx.x;
    const int lane = tid & 63;
    const int w    = tid >> 6;
    const int cB   = lane & 15;
    const int hi   = lane >> 4;
    const int qt = blockIdx.x, bh = blockIdx.y;
    const int b = bh >> 4, h = bh & 15;
    const int q0 = qt * 128;
    const long tokB = (long)b * S_LEN;

    const f16* Qb  = (const f16*)(g_buf + qOff);
    const f16* Kb  = (const f16*)(g_buf + kOff);
    const f16* Vtb = (const f16*)(g_buf + vtOff) + (long)bh * 64 * S_LEN;
    f16* Ob = (f16*)(g_buf + oOff);

    // Q fragments (resident for whole kernel)
    f16x8 qf[2][2];
#pragma unroll
    for (int m = 0; m < 2; ++m)
#pragma unroll
        for (int kk = 0; kk < 2; ++kk)
            qf[m][kk] = *(const f16x8*)&Qb[(tokB + q0 + w * 32 + m * 16 + cB) * DM + h * 64 + kk * 32 + hi * 8];

    f32x4 oacc[2][4] = {};
    float mrow[2][4], lrow[2][4];
#pragma unroll
    for (int m = 0; m < 2; ++m)
#pragma unroll
        for (int j = 0; j < 4; ++j) { mrow[m][j] = -1e30f; lrow[m][j] = 0.f; }

    const int r8 = lane >> 3;   // row within 8-row staging group
    const int c8 = lane & 7;    // 16B block within row
    const int nch = CAUSAL ? (qt * 2 + 2) : (S_LEN / 64);

    for (int c = 0; c < nch; ++c) {
        const int kv0 = c * 64;
        // ---- stage K[64 kv][64 d] and Vt[64 d][64 kv], swizzled source ----
#pragma unroll
        for (int t = 0; t < 2; ++t) {
            const int grp = w * 2 + t;             // 0..7
            const int row = grp * 8 + r8;          // 0..63
            const int sb  = c8 ^ (row & 7);
            __builtin_amdgcn_global_load_lds((const __attribute__((address_space(1))) void*)
                (Kb + (tokB + kv0 + row) * DM + h * 64 + sb * 8),
                (__attribute__((address_space(3))) void*)(Ks + grp * 512), 16, 0, 0);
            __builtin_amdgcn_global_load_lds((const __attribute__((address_space(1))) void*)
                (Vtb + (long)row * S_LEN + kv0 + sb * 8),
                (__attribute__((address_space(3))) void*)(Vs + grp * 512), 16, 0, 0);
        }
        __syncthreads();

        // ---- S = Q @ K^T (32 q x 64 kv per wave) ----
        f32x4 sacc[2][4] = {};
#pragma unroll
        for (int kk = 0; kk < 2; ++kk) {
            f16x8 kf[4];
#pragma unroll
            for (int n = 0; n < 4; ++n) {
                const int row = n * 16 + cB;
                const int t16 = (4 * kk + hi) ^ (row & 7);
                kf[n] = *(const f16x8*)((const char*)Ks + row * 128 + t16 * 16);
            }
#pragma unroll
            for (int m = 0; m < 2; ++m)
#pragma unroll
                for (int n = 0; n < 4; ++n)
                    sacc[m][n] = __builtin_amdgcn_mfma_f32_16x16x32_f16(qf[m][kk], kf[n], sacc[m][n], 0, 0, 0);
        }

        // ---- online softmax (rows owned per-thread at (m, hi*4+j)) ----
#pragma unroll
        for (int m = 0; m < 2; ++m) {
#pragma unroll
            for (int j = 0; j < 4; ++j) {
                float rmax = -1e30f;
#pragma unroll
                for (int n = 0; n < 4; ++n) {
                    float v = sacc[m][n][j] * 0.125f;
                    if (CAUSAL) {
                        const int qg = q0 + w * 32 + m * 16 + hi * 4 + j;
                        const int kg = kv0 + n * 16 + cB;
                        if (kg > qg) v = -1e30f;
                    }
                    sacc[m][n][j] = v;
                    rmax = fmaxf(rmax, v);
                }
                rmax = fmaxf(rmax, __shfl_xor(rmax, 1));
                rmax = fmaxf(rmax, __shfl_xor(rmax, 2));
                rmax = fmaxf(rmax, __shfl_xor(rmax, 4));
                rmax = fmaxf(rmax, __shfl_xor(rmax, 8));
                const float mo = mrow[m][j];
                const float mn = fmaxf(mo, rmax);
                const float alpha = __expf(mo - mn);
                float rsum = 0.f;
#pragma unroll
                for (int n = 0; n < 4; ++n) {
                    const float p = __expf(sacc[m][n][j] - mn);
                    sacc[m][n][j] = p;
                    rsum += p;
                }
                rsum += __shfl_xor(rsum, 1);
                rsum += __shfl_xor(rsum, 2);
                rsum += __shfl_xor(rsum, 4);
                rsum += __shfl_xor(rsum, 8);
                lrow[m][j] = lrow[m][j] * alpha + rsum;
                mrow[m][j] = mn;
#pragma unroll
                for (int nd = 0; nd < 4; ++nd) oacc[m][nd][j] *= alpha;
            }
        }

        // ---- P -> LDS (f16) for PV A-operand ----
#pragma unroll
        for (int m = 0; m < 2; ++m)
#pragma unroll
            for (int n = 0; n < 4; ++n)
#pragma unroll
                for (int j = 0; j < 4; ++j)
                    Ps[w][(m * 16 + hi * 4 + j) * 72 + n * 16 + cB] = (f16)sacc[m][n][j];

        // ---- O += P @ V ----
#pragma unroll
        for (int kk = 0; kk < 2; ++kk) {
            f16x8 pa[2], vf[4];
#pragma unroll
            for (int m = 0; m < 2; ++m)
                pa[m] = *(const f16x8*)&Ps[w][(m * 16 + cB) * 72 + kk * 32 + hi * 8];
#pragma unroll
            for (int nd = 0; nd < 4; ++nd) {
                const int d = nd * 16 + cB;
                const int t16 = (4 * kk + hi) ^ (d & 7);
                vf[nd] = *(const f16x8*)((const char*)Vs + d * 128 + t16 * 16);
            }
#pragma unroll
            for (int m = 0; m < 2; ++m)
#pragma unroll
                for (int nd = 0; nd < 4; ++nd)
                    oacc[m][nd] = __builtin_amdgcn_mfma_f32_16x16x32_f16(pa[m], vf[nd], oacc[m][nd], 0, 0, 0);
        }
        __syncthreads();
    }

    // ---- epilogue: normalize, repack via Ps, coalesced store ----
#pragma unroll
    for (int m = 0; m < 2; ++m)
#pragma unroll
        for (int j = 0; j < 4; ++j) {
            const float inv = 1.0f / lrow[m][j];
#pragma unroll
            for (int nd = 0; nd < 4; ++nd)
                Ps[w][(m * 16 + hi * 4 + j) * 72 + nd * 16 + cB] = (f16)(oacc[m][nd][j] * inv);
        }
    const int orow  = lane >> 1;
    const int ohalf = (lane & 1) * 32;
    f16* dst = Ob + (tokB + q0 + w * 32 + orow) * DM + h * 64 + ohalf;
    const f16* srcp = &Ps[w][orow * 72 + ohalf];
#pragma unroll
    for (int t = 0; t < 4; ++t)
        *(f16x8*)(dst + t * 8) = *(const f16x8*)(srcp + t * 8);
}

// ---------------------------------------------------------------------------
// fused residual-add + LayerNorm
// ---------------------------------------------------------------------------
__global__ __launch_bounds__(256) void ln_k(
    long inOff, const float* __restrict__ residExt, long residOff,
    const float* __restrict__ gamma, const float* __restrict__ beta,
    float* __restrict__ outFExt, long outFOff, long outHOff)
{
    const float* in    = (const float*)(g_buf + inOff);
    const float* resid = residExt ? residExt : (const float*)(g_buf + residOff);
    float* outF = outFExt ? outFExt : (float*)(g_buf + outFOff);
    f16*  outH = (f16*)(g_buf + outHOff);

    const long row = blockIdx.x;
    const int tid = threadIdx.x;
    const int lane = tid & 63, wid = tid >> 6;

    float4 a  = ((const float4*)(in    + row * DM))[tid];
    float4 rr = ((const float4*)(resid + row * DM))[tid];
    float x0 = a.x + rr.x, x1 = a.y + rr.y, x2 = a.z + rr.z, x3 = a.w + rr.w;

    __shared__ float red[4];
    float s = x0 + x1 + x2 + x3;
#pragma unroll
    for (int o = 32; o > 0; o >>= 1) s += __shfl_xor(s, o);
    if (lane == 0) red[wid] = s;
    __syncthreads();
    const float mu = (red[0] + red[1] + red[2] + red[3]) * (1.0f / DM);

    float d0 = x0 - mu, d1 = x1 - mu, d2 = x2 - mu, d3 = x3 - mu;
    float qq = d0*d0 + d1*d1 + d2*d2 + d3*d3;
#pragma unroll
    for (int o = 32; o > 0; o >>= 1) qq += __shfl_xor(qq, o);
    __syncthreads();
    if (lane == 0) red[wid] = qq;
    __syncthreads();
    const float var = (red[0] + red[1] + red[2] + red[3]) * (1.0f / DM);
    const float rs = rsqrtf(var + 1e-6f);

    float4 g  = ((const float4*)gamma)[tid];
    float4 be = ((const float4*)beta)[tid];
    float y0 = d0 * rs * g.x + be.x;
    float y1 = d1 * rs * g.y + be.y;
    float y2 = d2 * rs * g.z + be.z;
    float y3 = d3 * rs * g.w + be.w;

    ((float4*)(outF + row * DM))[tid] = make_float4(y0, y1, y2, y3);
    f16x4 hh; hh.x = (f16)y0; hh.y = (f16)y1; hh.z = (f16)y2; hh.w = (f16)y3;
    *(f16x4*)(outH + row * DM + tid * 4) = hh;
}

// ---------------------------------------------------------------------------
extern "C" void kernel_launch(void* const* d_in, const int* in_sizes, int n_in,
                              void* d_out, int out_size, void* d_ws, size_t ws_size,
                              hipStream_t stream)
{
    (void)in_sizes; (void)n_in; (void)d_ws; (void)ws_size; (void)out_size;
    const float* x   = (const float*)d_in[0];
    const float* enc = (const float*)d_in[1];
    const float* wq1 = (const float*)d_in[2];  const float* bq1 = (const float*)d_in[3];
    const float* wk1 = (const float*)d_in[4];  const float* bk1 = (const float*)d_in[5];
    const float* wv1 = (const float*)d_in[6];  const float* bv1 = (const float*)d_in[7];
    const float* wo1 = (const float*)d_in[8];  const float* bo1 = (const float*)d_in[9];
    const float* wq2 = (const float*)d_in[10]; const float* bq2 = (const float*)d_in[11];
    const float* wk2 = (const float*)d_in[12]; const float* bk2 = (const float*)d_in[13];
    const float* wv2 = (const float*)d_in[14]; const float* bv2 = (const float*)d_in[15];
    const float* wo2 = (const float*)d_in[16]; const float* bo2 = (const float*)d_in[17];
    const float* wf1 = (const float*)d_in[18]; const float* bf1 = (const float*)d_in[19];
    const float* wf2 = (const float*)d_in[20]; const float* bf2 = (const float*)d_in[21];
    const float* g1  = (const float*)d_in[22]; const float* be1 = (const float*)d_in[23];
    const float* g2  = (const float*)d_in[24]; const float* be2 = (const float*)d_in[25];
    const float* g3  = (const float*)d_in[26]; const float* be3 = (const float*)d_in[27];
    float* out = (float*)d_out;

    const dim3 T256(256), T32x8(32, 8);

    // ---- converts & weight transposes ----
    cvt_f32_f16_k<<<8192, T256, 0, stream>>>(x,   OFF_XB);
    cvt_f32_f16_k<<<8192, T256, 0, stream>>>(enc, OFF_ENC);
    transw_k<<<dim3(32, 32),  T32x8, 0, stream>>>(wq1, WQ1T, 1024, 1024);
    transw_k<<<dim3(32, 32),  T32x8, 0, stream>>>(wk1, WK1T, 1024, 1024);
    transw_k<<<dim3(32, 32),  T32x8, 0, stream>>>(wv1, WV1T, 1024, 1024);
    transw_k<<<dim3(32, 32),  T32x8, 0, stream>>>(wo1, WO1T, 1024, 1024);
    transw_k<<<dim3(32, 32),  T32x8, 0, stream>>>(wq2, WQ2T, 1024, 1024);
    transw_k<<<dim3(32, 32),  T32x8, 0, stream>>>(wk2, WK2T, 1024, 1024);
    transw_k<<<dim3(32, 32),  T32x8, 0, stream>>>(wv2, WV2T, 1024, 1024);
    transw_k<<<dim3(32, 32),  T32x8, 0, stream>>>(wo2, WO2T, 1024, 1024);
    transw_k<<<dim3(128, 32), T32x8, 0, stream>>>(wf1, WF1T, 1024, 4096);
    transw_k<<<dim3(32, 128), T32x8, 0, stream>>>(wf2, WF2T, 4096, 1024);

    // ---- masked self-attention ----
    gemm_k<128,128,0><<<dim3(8,64), T256, 0, stream>>>(OFF_XB, WQ1T, OFF_Q, bq1, 1024, 1024,1024,1024);
    gemm_k<128,128,0><<<dim3(8,64), T256, 0, stream>>>(OFF_XB, WK1T, OFF_K, bk1, 1024, 1024,1024,1024);
    gemm_k<128,128,0><<<dim3(8,64), T256, 0, stream>>>(OFF_XB, WV1T, OFF_V, bv1, 1024, 1024,1024,1024);
    transv_k<<<dim3(64,2,64), T32x8, 0, stream>>>(OFF_V, OFF_VT);
    flash_k<1><<<dim3(16,64), T256, 0, stream>>>(OFF_Q, OFF_K, OFF_VT, OFF_AC);
    gemm_k<128,128,2><<<dim3(8,64), T256, 0, stream>>>(OFF_AC, WO1T, OFF_F2, bo1, 1024, 1024,1024,1024);
    ln_k<<<8192, T256, 0, stream>>>(OFF_F2, x, 0, g1, be1, nullptr, OFF_F1, OFF_XB);

    // ---- cross-attention (q=enc, k=enc, v=x1) ----
    gemm_k<128,128,0><<<dim3(8,64), T256, 0, stream>>>(OFF_ENC, WQ2T, OFF_Q, bq2, 1024, 1024,1024,1024);
    gemm_k<128,128,0><<<dim3(8,64), T256, 0, stream>>>(OFF_ENC, WK2T, OFF_K, bk2, 1024, 1024,1024,1024);
    gemm_k<128,128,0><<<dim3(8,64), T256, 0, stream>>>(OFF_XB, WV2T, OFF_V, bv2, 1024, 1024,1024,1024);
    transv_k<<<dim3(64,2,64), T32x8, 0, stream>>>(OFF_V, OFF_VT);
    flash_k<0><<<dim3(16,64), T256, 0, stream>>>(OFF_Q, OFF_K, OFF_VT, OFF_AC);
    gemm_k<128,128,2><<<dim3(8,64), T256, 0, stream>>>(OFF_AC, WO2T, OFF_F2, bo2, 1024, 1024,1024,1024);
    ln_k<<<8192, T256, 0, stream>>>(OFF_F2, nullptr, OFF_F1, g2, be2, nullptr, OFF_F3, OFF_XB);

    // ---- feed-forward ----
    gemm_k<128,128,1><<<dim3(32,64), T256, 0, stream>>>(OFF_XB, WF1T, OFF_HID, bf1, 1024, 1024,1024,4096);
    gemm_k<128,128,2><<<dim3(8,64), T256, 0, stream>>>(OFF_HID, WF2T, OFF_F2, bf2, 4096, 4096,4096,1024);
    ln_k<<<8192, T256, 0, stream>>>(OFF_F2, nullptr, OFF_F3, g3, be3, out, 0, OFF_XB);
}

// Round 3
// 1030.128 us; speedup vs baseline: 1.4894x; 1.0277x over previous
//
#include <hip/hip_runtime.h>

// ---------------------------------------------------------------------------
// Decoder layer (B=4, S=2048, D=1024, H=16, Dh=64, FF=4096), f32 in/out.
// Internally: f16 MFMA GEMMs (f32 accum), f32 softmax/LN.
// Round 2: flash attention rework — 64-row blocks (2048 blocks, 3/CU),
// double-buffered K/V staging with counted vmcnt, exp2-domain softmax,
// mask only on the diagonal chunk, heavy-first causal ordering.
// ---------------------------------------------------------------------------

typedef _Float16 f16;
typedef _Float16 f16x8 __attribute__((ext_vector_type(8)));
typedef _Float16 f16x4 __attribute__((ext_vector_type(4)));
typedef float f32x4 __attribute__((ext_vector_type(4)));

constexpr int S_LEN = 2048;
constexpr int DM    = 1024;

// ---- static device arena (byte offsets) ----
constexpr long OFF_W   = 0;                // transposed weights f16 (32 MiB)
constexpr long OFF_XB  = 32L  << 20;       // current stream, f16 [8192,1024]
constexpr long OFF_ENC = 48L  << 20;       // encoder f16
constexpr long OFF_Q   = 64L  << 20;
constexpr long OFF_K   = 80L  << 20;
constexpr long OFF_V   = 96L  << 20;
constexpr long OFF_VT  = 112L << 20;       // V transposed per head [bh][64][S]
constexpr long OFF_AC  = 128L << 20;       // attention concat f16
constexpr long OFF_HID = 144L << 20;       // FF hidden f16 [8192,4096]
constexpr long OFF_F1  = 208L << 20;       // f32 [8192,1024]
constexpr long OFF_F2  = 240L << 20;       // f32
constexpr long OFF_F3  = 272L << 20;       // f32
constexpr long BUF_BYTES = 304L << 20;

__device__ alignas(4096) unsigned char g_buf[BUF_BYTES];

constexpr long WQ1T = OFF_W + (0L  << 20);
constexpr long WK1T = OFF_W + (2L  << 20);
constexpr long WV1T = OFF_W + (4L  << 20);
constexpr long WO1T = OFF_W + (6L  << 20);
constexpr long WQ2T = OFF_W + (8L  << 20);
constexpr long WK2T = OFF_W + (10L << 20);
constexpr long WV2T = OFF_W + (12L << 20);
constexpr long WO2T = OFF_W + (14L << 20);
constexpr long WF1T = OFF_W + (16L << 20);  // [4096][1024]
constexpr long WF2T = OFF_W + (24L << 20);  // [1024][4096]

// ---------------------------------------------------------------------------
__global__ __launch_bounds__(256) void cvt_f32_f16_k(const float* __restrict__ in, long outOff)
{
    f16* out = (f16*)(g_buf + outOff);
    long i = (long)blockIdx.x * 256 + threadIdx.x;
    float4 v = ((const float4*)in)[i];
    f16x4 h;
    h.x = (f16)v.x; h.y = (f16)v.y; h.z = (f16)v.z; h.w = (f16)v.w;
    *(f16x4*)(out + i * 4) = h;
}

// weight transpose + convert: W f32 [K,N] -> Wt f16 [N,K]
__global__ __launch_bounds__(256) void transw_k(const float* __restrict__ W, long outOff, int K, int N)
{
    __shared__ float t[32][33];
    f16* Wt = (f16*)(g_buf + outOff);
    int tx = threadIdx.x, ty = threadIdx.y;
    int c0 = blockIdx.x * 32, r0 = blockIdx.y * 32;
#pragma unroll
    for (int i = 0; i < 4; ++i)
        t[ty + 8*i][tx] = W[(long)(r0 + ty + 8*i) * N + c0 + tx];
    __syncthreads();
#pragma unroll
    for (int i = 0; i < 4; ++i)
        Wt[(long)(c0 + ty + 8*i) * K + r0 + tx] = (f16)t[tx][ty + 8*i];
}

// per-head V transpose: V f16 [b*S+s][h*64+d] -> Vt f16 [bh][d][s]
__global__ __launch_bounds__(256) void transv_k(long vOff, long vtOff)
{
    __shared__ f16 t[32][33];
    const f16* V = (const f16*)(g_buf + vOff);
    f16* Vt = (f16*)(g_buf + vtOff);
    int tx = threadIdx.x, ty = threadIdx.y;
    int bh = blockIdx.z; int b = bh >> 4, h = bh & 15;
    int s0 = blockIdx.x * 32, d0 = blockIdx.y * 32;
#pragma unroll
    for (int i = 0; i < 4; ++i)
        t[ty + 8*i][tx] = V[(long)(b * S_LEN + s0 + ty + 8*i) * DM + h * 64 + d0 + tx];
    __syncthreads();
#pragma unroll
    for (int i = 0; i < 4; ++i)
        Vt[((long)bh * 64 + d0 + ty + 8*i) * S_LEN + s0 + tx] = t[tx][ty + 8*i];
}

// ---------------------------------------------------------------------------
// GEMM: C[M,N] = A[M,K] @ Bt[N,K] (+bias / relu)
// MODE 0: f16 out + bias   MODE 1: f16 out + bias + relu   MODE 2: f32 out + bias
// ---------------------------------------------------------------------------
template<int BM, int BN, int MODE>
__global__ __launch_bounds__(256) void gemm_k(
    long aOff, long bOff, long cOff, const float* __restrict__ bias,
    int K, int lda, int ldb, int ldc)
{
    constexpr int FM = BM / 32;
    constexpr int FN = BN / 32;
    __shared__ f16 As[BM * 32];
    __shared__ f16 Bs[BN * 32];

    const int tid  = threadIdx.x;
    const int lane = tid & 63;
    const int wid  = tid >> 6;
    const int row0 = blockIdx.y * BM;
    const int col0 = blockIdx.x * BN;

    const f16* Ab = (const f16*)(g_buf + aOff);
    const f16* Bb = (const f16*)(g_buf + bOff);

    const int wr = (wid >> 1) * (BM / 2);
    const int wc = (wid & 1)  * (BN / 2);
    const int rB = (lane >> 4) * 4;
    const int cB = lane & 15;
    const int kg = (lane >> 4) * 8;

    f32x4 acc[FM][FN] = {};

    for (int kt = 0; kt < K / 32; ++kt) {
        const int kBase = kt * 32;
#pragma unroll
        for (int t = 0; t < BM / 64; ++t) {
            int i = wid + t * 4;
            const f16* gp = Ab + (long)(row0 + i * 16 + (lane >> 2)) * lda + kBase + (lane & 3) * 8;
            __builtin_amdgcn_global_load_lds((const __attribute__((address_space(1))) void*)gp,
                (__attribute__((address_space(3))) void*)(As + i * 512), 16, 0, 0);
        }
#pragma unroll
        for (int t = 0; t < BN / 64; ++t) {
            int i = wid + t * 4;
            const f16* gp = Bb + (long)(col0 + i * 16 + (lane >> 2)) * ldb + kBase + (lane & 3) * 8;
            __builtin_amdgcn_global_load_lds((const __attribute__((address_space(1))) void*)gp,
                (__attribute__((address_space(3))) void*)(Bs + i * 512), 16, 0, 0);
        }
        __syncthreads();

        f16x8 af[FM], bf[FN];
#pragma unroll
        for (int m = 0; m < FM; ++m)
            af[m] = *(const f16x8*)&As[(wr + m * 16 + cB) * 32 + kg];
#pragma unroll
        for (int n = 0; n < FN; ++n)
            bf[n] = *(const f16x8*)&Bs[(wc + n * 16 + cB) * 32 + kg];
#pragma unroll
        for (int m = 0; m < FM; ++m)
#pragma unroll
            for (int n = 0; n < FN; ++n)
                acc[m][n] = __builtin_amdgcn_mfma_f32_16x16x32_f16(af[m], bf[n], acc[m][n], 0, 0, 0);
        __syncthreads();
    }

    float* Cf = (float*)(g_buf + cOff);
    f16*  Ch = (f16*)(g_buf + cOff);
#pragma unroll
    for (int m = 0; m < FM; ++m) {
#pragma unroll
        for (int n = 0; n < FN; ++n) {
            const int c = col0 + wc + n * 16 + cB;
            const float bv = bias[c];
#pragma unroll
            for (int j = 0; j < 4; ++j) {
                const int r = row0 + wr + m * 16 + rB + j;
                float v = acc[m][n][j] + bv;
                if constexpr (MODE == 1) v = fmaxf(v, 0.f);
                const long idx = (long)r * ldc + c;
                if constexpr (MODE == 2) Cf[idx] = v;
                else                     Ch[idx] = (f16)v;
            }
        }
    }
}

// ---------------------------------------------------------------------------
// Fused flash attention, round-2 structure.
// Block = 64 q rows of one (b,h); 4 waves x 16 rows (FM=1). KV chunk = 64.
// K/V double-buffered in LDS (global_load_lds, pre-swizzled source);
// counted vmcnt(4) + raw barriers so next-chunk staging overlaps compute.
// Softmax in exp2 domain (scale*log2e folded into Q fragments).
// ---------------------------------------------------------------------------
template<int CAUSAL>
__global__ __launch_bounds__(256) void flash_k(long qOff, long kOff, long vtOff, long oOff)
{
    __shared__ alignas(16) f16 Ks[2][64 * 64];
    __shared__ alignas(16) f16 Vs[2][64 * 64];
    __shared__ alignas(16) f16 Ps[4][16 * 72];

    const int tid  = threadIdx.x;
    const int lane = tid & 63;
    const int w    = tid >> 6;
    const int cB   = lane & 15;
    const int hi   = lane >> 4;
    const int qt   = CAUSAL ? (31 - blockIdx.x) : blockIdx.x;   // heavy-first for causal
    const int bh   = blockIdx.y;
    const int b = bh >> 4, h = bh & 15;
    const int q0 = qt * 64;
    const long tokB = (long)b * S_LEN;

    const f16* Qb  = (const f16*)(g_buf + qOff);
    const f16* Kb  = (const f16*)(g_buf + kOff);
    const f16* Vtb = (const f16*)(g_buf + vtOff) + (long)bh * 64 * S_LEN;
    f16* Ob = (f16*)(g_buf + oOff);

    const int r8 = lane >> 3;   // row within 8-row staging group
    const int c8 = lane & 7;    // 16B block within row
    const int sb = c8 ^ r8;     // swizzled source block ((row&7)==r8)
    const int nch = CAUSAL ? (qt + 1) : (S_LEN / 64);

    auto stage = [&](int buf, int c) {
        const int kv0 = c * 64;
#pragma unroll
        for (int t = 0; t < 2; ++t) {
            const int grp = w * 2 + t;
            const int row = grp * 8 + r8;
            __builtin_amdgcn_global_load_lds((const __attribute__((address_space(1))) void*)
                (Kb + (tokB + kv0 + row) * DM + h * 64 + sb * 8),
                (__attribute__((address_space(3))) void*)(&Ks[buf][grp * 512]), 16, 0, 0);
            __builtin_amdgcn_global_load_lds((const __attribute__((address_space(1))) void*)
                (Vtb + (long)row * S_LEN + kv0 + sb * 8),
                (__attribute__((address_space(3))) void*)(&Vs[buf][grp * 512]), 16, 0, 0);
        }
    };

    stage(0, 0);

    // Q fragments, pre-scaled by 1/sqrt(Dh) * log2(e) (softmax runs in exp2)
    f16x8 qf[2];
    const f16 hscale = (f16)(0.125f * 1.44269504088896f);
#pragma unroll
    for (int kk = 0; kk < 2; ++kk) {
        qf[kk] = *(const f16x8*)&Qb[(tokB + q0 + w * 16 + cB) * DM + h * 64 + kk * 32 + hi * 8];
#pragma unroll
        for (int i = 0; i < 8; ++i) qf[kk][i] = qf[kk][i] * hscale;
    }

    f32x4 oacc[4] = {};
    float mrow[4], lrow[4];
#pragma unroll
    for (int j = 0; j < 4; ++j) { mrow[j] = -1e30f; lrow[j] = 0.f; }

    for (int c = 0; c < nch; ++c) {
        const int cur = c & 1;
        const int kv0 = c * 64;
        if (c + 1 < nch) {
            stage(cur ^ 1, c + 1);
            asm volatile("s_waitcnt vmcnt(4)" ::: "memory");
        } else {
            asm volatile("s_waitcnt vmcnt(0)" ::: "memory");
        }
        __builtin_amdgcn_s_barrier();
        __builtin_amdgcn_sched_barrier(0);

        // ---- S = Q @ K^T (16 q x 64 kv per wave) ----
        f32x4 sacc[4] = {};
#pragma unroll
        for (int kk = 0; kk < 2; ++kk) {
            f16x8 kf[4];
#pragma unroll
            for (int n = 0; n < 4; ++n) {
                const int row = n * 16 + cB;
                const int t16 = (4 * kk + hi) ^ (row & 7);
                kf[n] = *(const f16x8*)((const char*)&Ks[cur][0] + row * 128 + t16 * 16);
            }
#pragma unroll
            for (int n = 0; n < 4; ++n)
                sacc[n] = __builtin_amdgcn_mfma_f32_16x16x32_f16(qf[kk], kf[n], sacc[n], 0, 0, 0);
        }

        // ---- online softmax (exp2 domain); mask only on diagonal chunk ----
        const bool domask = CAUSAL && (c == nch - 1);
#pragma unroll
        for (int j = 0; j < 4; ++j) {
            if (domask) {
                const int qg = q0 + w * 16 + hi * 4 + j;
#pragma unroll
                for (int n = 0; n < 4; ++n)
                    if (kv0 + n * 16 + cB > qg) sacc[n][j] = -1e30f;
            }
            float rmax = fmaxf(fmaxf(sacc[0][j], sacc[1][j]), fmaxf(sacc[2][j], sacc[3][j]));
            rmax = fmaxf(rmax, __shfl_xor(rmax, 1));
            rmax = fmaxf(rmax, __shfl_xor(rmax, 2));
            rmax = fmaxf(rmax, __shfl_xor(rmax, 4));
            rmax = fmaxf(rmax, __shfl_xor(rmax, 8));
            const float mo = mrow[j];
            const float mn = fmaxf(mo, rmax);
            const float alpha = __builtin_amdgcn_exp2f(mo - mn);
            float rsum = 0.f;
#pragma unroll
            for (int n = 0; n < 4; ++n) {
                const float p = __builtin_amdgcn_exp2f(sacc[n][j] - mn);
                sacc[n][j] = p;
                rsum += p;
            }
            rsum += __shfl_xor(rsum, 1);
            rsum += __shfl_xor(rsum, 2);
            rsum += __shfl_xor(rsum, 4);
            rsum += __shfl_xor(rsum, 8);
            lrow[j] = lrow[j] * alpha + rsum;
            mrow[j] = mn;
#pragma unroll
            for (int nd = 0; nd < 4; ++nd) oacc[nd][j] *= alpha;
        }

        // ---- P -> LDS (f16) for PV A-operand ----
#pragma unroll
        for (int n = 0; n < 4; ++n)
#pragma unroll
            for (int j = 0; j < 4; ++j)
                Ps[w][(hi * 4 + j) * 72 + n * 16 + cB] = (f16)sacc[n][j];

        // ---- O += P @ V ----
#pragma unroll
        for (int kk = 0; kk < 2; ++kk) {
            f16x8 pa = *(const f16x8*)&Ps[w][cB * 72 + kk * 32 + hi * 8];
            f16x8 vf[4];
#pragma unroll
            for (int nd = 0; nd < 4; ++nd) {
                const int d = nd * 16 + cB;
                const int t16 = (4 * kk + hi) ^ (d & 7);
                vf[nd] = *(const f16x8*)((const char*)&Vs[cur][0] + d * 128 + t16 * 16);
            }
#pragma unroll
            for (int nd = 0; nd < 4; ++nd)
                oacc[nd] = __builtin_amdgcn_mfma_f32_16x16x32_f16(pa, vf[nd], oacc[nd], 0, 0, 0);
        }
        asm volatile("s_waitcnt lgkmcnt(0)" ::: "memory");
        __builtin_amdgcn_sched_barrier(0);
        __builtin_amdgcn_s_barrier();
        __builtin_amdgcn_sched_barrier(0);
    }

    // ---- epilogue: normalize, repack via Ps, coalesced store ----
#pragma unroll
    for (int j = 0; j < 4; ++j) {
        const float inv = 1.0f / lrow[j];
#pragma unroll
        for (int nd = 0; nd < 4; ++nd)
            Ps[w][(hi * 4 + j) * 72 + nd * 16 + cB] = (f16)(oacc[nd][j] * inv);
    }
    const int orow = lane >> 2;
    const int od   = (lane & 3) * 16;
    f16* dst = Ob + (tokB + q0 + w * 16 + orow) * DM + h * 64 + od;
    const f16* srcp = &Ps[w][orow * 72 + od];
    *(f16x8*)(dst)     = *(const f16x8*)(srcp);
    *(f16x8*)(dst + 8) = *(const f16x8*)(srcp + 8);
}

// ---------------------------------------------------------------------------
// fused residual-add + LayerNorm
// ---------------------------------------------------------------------------
__global__ __launch_bounds__(256) void ln_k(
    long inOff, const float* __restrict__ residExt, long residOff,
    const float* __restrict__ gamma, const float* __restrict__ beta,
    float* __restrict__ outFExt, long outFOff, long outHOff)
{
    const float* in    = (const float*)(g_buf + inOff);
    const float* resid = residExt ? residExt : (const float*)(g_buf + residOff);
    float* outF = outFExt ? outFExt : (float*)(g_buf + outFOff);
    f16*  outH = (f16*)(g_buf + outHOff);

    const long row = blockIdx.x;
    const int tid = threadIdx.x;
    const int lane = tid & 63, wid = tid >> 6;

    float4 a  = ((const float4*)(in    + row * DM))[tid];
    float4 rr = ((const float4*)(resid + row * DM))[tid];
    float x0 = a.x + rr.x, x1 = a.y + rr.y, x2 = a.z + rr.z, x3 = a.w + rr.w;

    __shared__ float red[4];
    float s = x0 + x1 + x2 + x3;
#pragma unroll
    for (int o = 32; o > 0; o >>= 1) s += __shfl_xor(s, o);
    if (lane == 0) red[wid] = s;
    __syncthreads();
    const float mu = (red[0] + red[1] + red[2] + red[3]) * (1.0f / DM);

    float d0 = x0 - mu, d1 = x1 - mu, d2 = x2 - mu, d3 = x3 - mu;
    float qq = d0*d0 + d1*d1 + d2*d2 + d3*d3;
#pragma unroll
    for (int o = 32; o > 0; o >>= 1) qq += __shfl_xor(qq, o);
    __syncthreads();
    if (lane == 0) red[wid] = qq;
    __syncthreads();
    const float var = (red[0] + red[1] + red[2] + red[3]) * (1.0f / DM);
    const float rs = rsqrtf(var + 1e-6f);

    float4 g  = ((const float4*)gamma)[tid];
    float4 be = ((const float4*)beta)[tid];
    float y0 = d0 * rs * g.x + be.x;
    float y1 = d1 * rs * g.y + be.y;
    float y2 = d2 * rs * g.z + be.z;
    float y3 = d3 * rs * g.w + be.w;

    ((float4*)(outF + row * DM))[tid] = make_float4(y0, y1, y2, y3);
    f16x4 hh; hh.x = (f16)y0; hh.y = (f16)y1; hh.z = (f16)y2; hh.w = (f16)y3;
    *(f16x4*)(outH + row * DM + tid * 4) = hh;
}

// ---------------------------------------------------------------------------
extern "C" void kernel_launch(void* const* d_in, const int* in_sizes, int n_in,
                              void* d_out, int out_size, void* d_ws, size_t ws_size,
                              hipStream_t stream)
{
    (void)in_sizes; (void)n_in; (void)d_ws; (void)ws_size; (void)out_size;
    const float* x   = (const float*)d_in[0];
    const float* enc = (const float*)d_in[1];
    const float* wq1 = (const float*)d_in[2];  const float* bq1 = (const float*)d_in[3];
    const float* wk1 = (const float*)d_in[4];  const float* bk1 = (const float*)d_in[5];
    const float* wv1 = (const float*)d_in[6];  const float* bv1 = (const float*)d_in[7];
    const float* wo1 = (const float*)d_in[8];  const float* bo1 = (const float*)d_in[9];
    const float* wq2 = (const float*)d_in[10]; const float* bq2 = (const float*)d_in[11];
    const float* wk2 = (const float*)d_in[12]; const float* bk2 = (const float*)d_in[13];
    const float* wv2 = (const float*)d_in[14]; const float* bv2 = (const float*)d_in[15];
    const float* wo2 = (const float*)d_in[16]; const float* bo2 = (const float*)d_in[17];
    const float* wf1 = (const float*)d_in[18]; const float* bf1 = (const float*)d_in[19];
    const float* wf2 = (const float*)d_in[20]; const float* bf2 = (const float*)d_in[21];
    const float* g1  = (const float*)d_in[22]; const float* be1 = (const float*)d_in[23];
    const float* g2  = (const float*)d_in[24]; const float* be2 = (const float*)d_in[25];
    const float* g3  = (const float*)d_in[26]; const float* be3 = (const float*)d_in[27];
    float* out = (float*)d_out;

    const dim3 T256(256), T32x8(32, 8);

    // ---- converts & weight transposes ----
    cvt_f32_f16_k<<<8192, T256, 0, stream>>>(x,   OFF_XB);
    cvt_f32_f16_k<<<8192, T256, 0, stream>>>(enc, OFF_ENC);
    transw_k<<<dim3(32, 32),  T32x8, 0, stream>>>(wq1, WQ1T, 1024, 1024);
    transw_k<<<dim3(32, 32),  T32x8, 0, stream>>>(wk1, WK1T, 1024, 1024);
    transw_k<<<dim3(32, 32),  T32x8, 0, stream>>>(wv1, WV1T, 1024, 1024);
    transw_k<<<dim3(32, 32),  T32x8, 0, stream>>>(wo1, WO1T, 1024, 1024);
    transw_k<<<dim3(32, 32),  T32x8, 0, stream>>>(wq2, WQ2T, 1024, 1024);
    transw_k<<<dim3(32, 32),  T32x8, 0, stream>>>(wk2, WK2T, 1024, 1024);
    transw_k<<<dim3(32, 32),  T32x8, 0, stream>>>(wv2, WV2T, 1024, 1024);
    transw_k<<<dim3(32, 32),  T32x8, 0, stream>>>(wo2, WO2T, 1024, 1024);
    transw_k<<<dim3(128, 32), T32x8, 0, stream>>>(wf1, WF1T, 1024, 4096);
    transw_k<<<dim3(32, 128), T32x8, 0, stream>>>(wf2, WF2T, 4096, 1024);

    // ---- masked self-attention ----
    gemm_k<128,128,0><<<dim3(8,64), T256, 0, stream>>>(OFF_XB, WQ1T, OFF_Q, bq1, 1024, 1024,1024,1024);
    gemm_k<128,128,0><<<dim3(8,64), T256, 0, stream>>>(OFF_XB, WK1T, OFF_K, bk1, 1024, 1024,1024,1024);
    gemm_k<128,128,0><<<dim3(8,64), T256, 0, stream>>>(OFF_XB, WV1T, OFF_V, bv1, 1024, 1024,1024,1024);
    transv_k<<<dim3(64,2,64), T32x8, 0, stream>>>(OFF_V, OFF_VT);
    flash_k<1><<<dim3(32,64), T256, 0, stream>>>(OFF_Q, OFF_K, OFF_VT, OFF_AC);
    gemm_k<128,128,2><<<dim3(8,64), T256, 0, stream>>>(OFF_AC, WO1T, OFF_F2, bo1, 1024, 1024,1024,1024);
    ln_k<<<8192, T256, 0, stream>>>(OFF_F2, x, 0, g1, be1, nullptr, OFF_F1, OFF_XB);

    // ---- cross-attention (q=enc, k=enc, v=x1) ----
    gemm_k<128,128,0><<<dim3(8,64), T256, 0, stream>>>(OFF_ENC, WQ2T, OFF_Q, bq2, 1024, 1024,1024,1024);
    gemm_k<128,128,0><<<dim3(8,64), T256, 0, stream>>>(OFF_ENC, WK2T, OFF_K, bk2, 1024, 1024,1024,1024);
    gemm_k<128,128,0><<<dim3(8,64), T256, 0, stream>>>(OFF_XB, WV2T, OFF_V, bv2, 1024, 1024,1024,1024);
    transv_k<<<dim3(64,2,64), T32x8, 0, stream>>>(OFF_V, OFF_VT);
    flash_k<0><<<dim3(32,64), T256, 0, stream>>>(OFF_Q, OFF_K, OFF_VT, OFF_AC);
    gemm_k<128,128,2><<<dim3(8,64), T256, 0, stream>>>(OFF_AC, WO2T, OFF_F2, bo2, 1024, 1024,1024,1024);
    ln_k<<<8192, T256, 0, stream>>>(OFF_F2, nullptr, OFF_F1, g2, be2, nullptr, OFF_F3, OFF_XB);

    // ---- feed-forward ----
    gemm_k<128,128,1><<<dim3(32,64), T256, 0, stream>>>(OFF_XB, WF1T, OFF_HID, bf1, 1024, 1024,1024,4096);
    gemm_k<128,128,2><<<dim3(8,64), T256, 0, stream>>>(OFF_HID, WF2T, OFF_F2, bf2, 4096, 4096,4096,1024);
    ln_k<<<8192, T256, 0, stream>>>(OFF_F2, nullptr, OFF_F3, g3, be3, out, 0, OFF_XB);
}

// Round 4
// 824.259 us; speedup vs baseline: 1.8614x; 1.2498x over previous
//
#include <hip/hip_runtime.h>

// ---------------------------------------------------------------------------
// Decoder layer (B=4, S=2048, D=1024, H=16, Dh=64, FF=4096), f32 in/out.
// Round 3: flash attention rebuilt on swapped-operand 32x32 MFMA:
// lane owns a full q-row -> in-lane softmax, in-register P (no LDS round-trip),
// defer-rescale (THR=8, exp2 domain), per-wave skip of fully-masked chunks.
// ---------------------------------------------------------------------------

typedef _Float16 f16;
typedef _Float16 f16x8 __attribute__((ext_vector_type(8)));
typedef _Float16 f16x4 __attribute__((ext_vector_type(4)));
typedef float f32x4 __attribute__((ext_vector_type(4)));
typedef float f32x16 __attribute__((ext_vector_type(16)));
typedef unsigned int u32;

constexpr int S_LEN = 2048;
constexpr int DM    = 1024;

// ---- static device arena (byte offsets) ----
constexpr long OFF_W   = 0;                // transposed weights f16 (32 MiB)
constexpr long OFF_XB  = 32L  << 20;       // current stream, f16 [8192,1024]
constexpr long OFF_ENC = 48L  << 20;       // encoder f16
constexpr long OFF_Q   = 64L  << 20;
constexpr long OFF_K   = 80L  << 20;
constexpr long OFF_V   = 96L  << 20;
constexpr long OFF_VT  = 112L << 20;       // V transposed per head [bh][64][S]
constexpr long OFF_AC  = 128L << 20;       // attention concat f16
constexpr long OFF_HID = 144L << 20;       // FF hidden f16 [8192,4096]
constexpr long OFF_F1  = 208L << 20;       // f32 [8192,1024]
constexpr long OFF_F2  = 240L << 20;       // f32
constexpr long OFF_F3  = 272L << 20;       // f32
constexpr long BUF_BYTES = 304L << 20;

__device__ alignas(4096) unsigned char g_buf[BUF_BYTES];

constexpr long WQ1T = OFF_W + (0L  << 20);
constexpr long WK1T = OFF_W + (2L  << 20);
constexpr long WV1T = OFF_W + (4L  << 20);
constexpr long WO1T = OFF_W + (6L  << 20);
constexpr long WQ2T = OFF_W + (8L  << 20);
constexpr long WK2T = OFF_W + (10L << 20);
constexpr long WV2T = OFF_W + (12L << 20);
constexpr long WO2T = OFF_W + (14L << 20);
constexpr long WF1T = OFF_W + (16L << 20);  // [4096][1024]
constexpr long WF2T = OFF_W + (24L << 20);  // [1024][4096]

// ---------------------------------------------------------------------------
__global__ __launch_bounds__(256) void cvt_f32_f16_k(const float* __restrict__ in, long outOff)
{
    f16* out = (f16*)(g_buf + outOff);
    long i = (long)blockIdx.x * 256 + threadIdx.x;
    float4 v = ((const float4*)in)[i];
    f16x4 h;
    h.x = (f16)v.x; h.y = (f16)v.y; h.z = (f16)v.z; h.w = (f16)v.w;
    *(f16x4*)(out + i * 4) = h;
}

// weight transpose + convert: W f32 [K,N] -> Wt f16 [N,K]
__global__ __launch_bounds__(256) void transw_k(const float* __restrict__ W, long outOff, int K, int N)
{
    __shared__ float t[32][33];
    f16* Wt = (f16*)(g_buf + outOff);
    int tx = threadIdx.x, ty = threadIdx.y;
    int c0 = blockIdx.x * 32, r0 = blockIdx.y * 32;
#pragma unroll
    for (int i = 0; i < 4; ++i)
        t[ty + 8*i][tx] = W[(long)(r0 + ty + 8*i) * N + c0 + tx];
    __syncthreads();
#pragma unroll
    for (int i = 0; i < 4; ++i)
        Wt[(long)(c0 + ty + 8*i) * K + r0 + tx] = (f16)t[tx][ty + 8*i];
}

// per-head V transpose: V f16 [b*S+s][h*64+d] -> Vt f16 [bh][d][s]
__global__ __launch_bounds__(256) void transv_k(long vOff, long vtOff)
{
    __shared__ f16 t[32][33];
    const f16* V = (const f16*)(g_buf + vOff);
    f16* Vt = (f16*)(g_buf + vtOff);
    int tx = threadIdx.x, ty = threadIdx.y;
    int bh = blockIdx.z; int b = bh >> 4, h = bh & 15;
    int s0 = blockIdx.x * 32, d0 = blockIdx.y * 32;
#pragma unroll
    for (int i = 0; i < 4; ++i)
        t[ty + 8*i][tx] = V[(long)(b * S_LEN + s0 + ty + 8*i) * DM + h * 64 + d0 + tx];
    __syncthreads();
#pragma unroll
    for (int i = 0; i < 4; ++i)
        Vt[((long)bh * 64 + d0 + ty + 8*i) * S_LEN + s0 + tx] = t[tx][ty + 8*i];
}

// ---------------------------------------------------------------------------
// GEMM: C[M,N] = A[M,K] @ Bt[N,K] (+bias / relu)
// MODE 0: f16 out + bias   MODE 1: f16 out + bias + relu   MODE 2: f32 out + bias
// ---------------------------------------------------------------------------
template<int BM, int BN, int MODE>
__global__ __launch_bounds__(256) void gemm_k(
    long aOff, long bOff, long cOff, const float* __restrict__ bias,
    int K, int lda, int ldb, int ldc)
{
    constexpr int FM = BM / 32;
    constexpr int FN = BN / 32;
    __shared__ f16 As[BM * 32];
    __shared__ f16 Bs[BN * 32];

    const int tid  = threadIdx.x;
    const int lane = tid & 63;
    const int wid  = tid >> 6;
    const int row0 = blockIdx.y * BM;
    const int col0 = blockIdx.x * BN;

    const f16* Ab = (const f16*)(g_buf + aOff);
    const f16* Bb = (const f16*)(g_buf + bOff);

    const int wr = (wid >> 1) * (BM / 2);
    const int wc = (wid & 1)  * (BN / 2);
    const int rB = (lane >> 4) * 4;
    const int cB = lane & 15;
    const int kg = (lane >> 4) * 8;

    f32x4 acc[FM][FN] = {};

    for (int kt = 0; kt < K / 32; ++kt) {
        const int kBase = kt * 32;
#pragma unroll
        for (int t = 0; t < BM / 64; ++t) {
            int i = wid + t * 4;
            const f16* gp = Ab + (long)(row0 + i * 16 + (lane >> 2)) * lda + kBase + (lane & 3) * 8;
            __builtin_amdgcn_global_load_lds((const __attribute__((address_space(1))) void*)gp,
                (__attribute__((address_space(3))) void*)(As + i * 512), 16, 0, 0);
        }
#pragma unroll
        for (int t = 0; t < BN / 64; ++t) {
            int i = wid + t * 4;
            const f16* gp = Bb + (long)(col0 + i * 16 + (lane >> 2)) * ldb + kBase + (lane & 3) * 8;
            __builtin_amdgcn_global_load_lds((const __attribute__((address_space(1))) void*)gp,
                (__attribute__((address_space(3))) void*)(Bs + i * 512), 16, 0, 0);
        }
        __syncthreads();

        f16x8 af[FM], bf[FN];
#pragma unroll
        for (int m = 0; m < FM; ++m)
            af[m] = *(const f16x8*)&As[(wr + m * 16 + cB) * 32 + kg];
#pragma unroll
        for (int n = 0; n < FN; ++n)
            bf[n] = *(const f16x8*)&Bs[(wc + n * 16 + cB) * 32 + kg];
#pragma unroll
        for (int m = 0; m < FM; ++m)
#pragma unroll
            for (int n = 0; n < FN; ++n)
                acc[m][n] = __builtin_amdgcn_mfma_f32_16x16x32_f16(af[m], bf[n], acc[m][n], 0, 0, 0);
        __syncthreads();
    }

    float* Cf = (float*)(g_buf + cOff);
    f16*  Ch = (f16*)(g_buf + cOff);
#pragma unroll
    for (int m = 0; m < FM; ++m) {
#pragma unroll
        for (int n = 0; n < FN; ++n) {
            const int c = col0 + wc + n * 16 + cB;
            const float bv = bias[c];
#pragma unroll
            for (int j = 0; j < 4; ++j) {
                const int r = row0 + wr + m * 16 + rB + j;
                float v = acc[m][n][j] + bv;
                if constexpr (MODE == 1) v = fmaxf(v, 0.f);
                const long idx = (long)r * ldc + c;
                if constexpr (MODE == 2) Cf[idx] = v;
                else                     Ch[idx] = (f16)v;
            }
        }
    }
}

// ---------------------------------------------------------------------------
// Fused flash attention, swapped-operand 32x32 structure.
// Block = 128 q rows of one (b,h); 4 waves x 32 rows. KV chunk = 64.
// QK^T computed as mfma(K, Q) -> S^T: lane owns q-row (col=lane&31), holds
// kv = 32v + (r&3)+8(r>>2)+4(lane>>5) in p[v][r]. Softmax fully in-lane
// (one shfl_xor(32) per reduce). P packed to f16 in-register; half-exchange
// via 8 shfl_xor(32) builds PV A-fragments. Defer-rescale THR=8 (exp2 dom).
// ---------------------------------------------------------------------------
template<int CAUSAL>
__global__ __launch_bounds__(256, 3) void flash_k(long qOff, long kOff, long vtOff, long oOff)
{
    __shared__ alignas(16) f16 KV[2][2][4096];   // [buf][K/V][64*64]

    const int tid  = threadIdx.x;
    const int lane = tid & 63;
    const int w    = tid >> 6;
    const int ql   = lane & 31;      // q within wave tile (and V/K row selector)
    const int s    = lane >> 5;      // lane half
    const int qt   = CAUSAL ? (15 - (int)blockIdx.x) : (int)blockIdx.x;
    const int bh   = blockIdx.y;
    const int b = bh >> 4, h = bh & 15;
    const int q0 = qt * 128;
    const long tokB = (long)b * S_LEN;

    const f16* Qb  = (const f16*)(g_buf + qOff);
    const f16* Kb  = (const f16*)(g_buf + kOff);
    const f16* Vtb = (const f16*)(g_buf + vtOff) + (long)bh * 64 * S_LEN;
    f16* Ob = (f16*)(g_buf + oOff);

    const int r8 = lane >> 3;
    const int c8 = lane & 7;
    const int sb = c8 ^ r8;          // pre-swizzled source 16B block
    const int nch = CAUSAL ? 2 * (qt + 1) : (S_LEN / 64);

    auto stage = [&](int buf, int c) {
        const int kv0s = c * 64;
#pragma unroll
        for (int t = 0; t < 2; ++t) {
            const int grp = w * 2 + t;
            const int row = grp * 8 + r8;
            __builtin_amdgcn_global_load_lds(
                (const __attribute__((address_space(1))) void*)(Kb + (tokB + kv0s + row) * DM + h * 64 + sb * 8),
                (__attribute__((address_space(3))) void*)(&KV[buf][0][grp * 512]), 16, 0, 0);
            __builtin_amdgcn_global_load_lds(
                (const __attribute__((address_space(1))) void*)(Vtb + (long)row * S_LEN + kv0s + sb * 8),
                (__attribute__((address_space(3))) void*)(&KV[buf][1][grp * 512]), 16, 0, 0);
        }
    };

    stage(0, 0);

    // Q B-fragments, pre-scaled by 1/sqrt(Dh) * log2(e) (softmax in exp2 dom)
    f16x8 qf[4];
    {
        const f16 hs = (f16)(0.125f * 1.44269504088896f);
        const f16* qrow = Qb + (tokB + q0 + w * 32 + ql) * DM + h * 64 + s * 8;
#pragma unroll
        for (int kk = 0; kk < 4; ++kk) {
            qf[kk] = *(const f16x8*)(qrow + kk * 16);
#pragma unroll
            for (int i = 0; i < 8; ++i) qf[kk][i] = qf[kk][i] * hs;
        }
    }

    f32x16 oacc[2] = {};
    float mrow = -1e30f, lrow = 0.f;

    for (int c = 0; c < nch; ++c) {
        const int cur = c & 1;
        const int kv0 = c * 64;
        if (c + 1 < nch) {
            stage(cur ^ 1, c + 1);
            asm volatile("s_waitcnt vmcnt(4)" ::: "memory");
        } else {
            asm volatile("s_waitcnt vmcnt(0)" ::: "memory");
        }
        __builtin_amdgcn_s_barrier();
        __builtin_amdgcn_sched_barrier(0);

        const bool active = !CAUSAL || (kv0 <= q0 + w * 32 + 31);
        if (active) {
            // ---- S^T = K @ Q^T (lane: col q = ql, rows kv in regs) ----
            f32x16 p[2] = {};
#pragma unroll
            for (int kk = 0; kk < 4; ++kk) {
                const int t16 = (kk * 2 + s) ^ (ql & 7);
                f16x8 kf0 = *(const f16x8*)((const char*)&KV[cur][0][0] + ql * 128 + t16 * 16);
                f16x8 kf1 = *(const f16x8*)((const char*)&KV[cur][0][0] + (32 + ql) * 128 + t16 * 16);
                p[0] = __builtin_amdgcn_mfma_f32_32x32x16_f16(kf0, qf[kk], p[0], 0, 0, 0);
                p[1] = __builtin_amdgcn_mfma_f32_32x32x16_f16(kf1, qf[kk], p[1], 0, 0, 0);
            }

            // causal mask (diagonal region only; wave-uniform branch)
            if (CAUSAL && (kv0 + 63 > q0 + w * 32)) {
                const int q = q0 + w * 32 + ql;
#pragma unroll
                for (int v = 0; v < 2; ++v)
#pragma unroll
                    for (int r = 0; r < 16; ++r) {
                        const int kv = kv0 + v * 32 + (r & 3) + 8 * (r >> 2) + 4 * s;
                        if (kv > q) p[v][r] = -1e30f;
                    }
            }

            // ---- online softmax, in-lane row ----
            float rmax = p[0][0];
#pragma unroll
            for (int r = 1; r < 16; ++r) rmax = fmaxf(rmax, p[0][r]);
#pragma unroll
            for (int r = 0; r < 16; ++r) rmax = fmaxf(rmax, p[1][r]);
            rmax = fmaxf(rmax, __shfl_xor(rmax, 32));

            if (!__all(rmax <= mrow + 8.0f)) {          // defer-rescale (THR=8)
                const float mn = fmaxf(mrow, rmax);
                const float alpha = __builtin_amdgcn_exp2f(mrow - mn);
                lrow *= alpha;
                mrow = mn;
#pragma unroll
                for (int r = 0; r < 16; ++r) {
                    const int qr = (r & 3) + 8 * (r >> 2) + 4 * s;
                    const float ab = __shfl(alpha, qr);  // alpha for D-row qr
                    oacc[0][r] *= ab;
                    oacc[1][r] *= ab;
                }
            }

            float rsum = 0.f;
#pragma unroll
            for (int v = 0; v < 2; ++v)
#pragma unroll
                for (int r = 0; r < 16; ++r) {
                    const float pe = __builtin_amdgcn_exp2f(p[v][r] - mrow);
                    p[v][r] = pe;
                    rsum += pe;
                }
            rsum += __shfl_xor(rsum, 32);
            lrow += rsum;

            // ---- pack P rows to f16 pairs (in-register) ----
            u32 pk[2][4][2];
#pragma unroll
            for (int v = 0; v < 2; ++v)
#pragma unroll
                for (int a = 0; a < 4; ++a)
#pragma unroll
                    for (int cc = 0; cc < 2; ++cc) {
                        union { f16 hh[2]; u32 u; } t;
                        t.hh[0] = (f16)p[v][4 * a + 2 * cc];
                        t.hh[1] = (f16)p[v][4 * a + 2 * cc + 1];
                        pk[v][a][cc] = t.u;
                    }
            // half-exchange: partner needs a = 2k1 + (s^1); we need a = 2k1 + s
            u32 loc[2][2][2], exv[2][2][2];
#pragma unroll
            for (int v = 0; v < 2; ++v)
#pragma unroll
                for (int k1 = 0; k1 < 2; ++k1)
#pragma unroll
                    for (int cc = 0; cc < 2; ++cc) {
                        const u32 pe = pk[v][2 * k1][cc];
                        const u32 po = pk[v][2 * k1 + 1][cc];
                        loc[v][k1][cc] = s ? po : pe;
                        const u32 snd = s ? pe : po;
                        exv[v][k1][cc] = (u32)__shfl_xor((int)snd, 32);
                    }

            // ---- O += P @ V ----
#pragma unroll
            for (int ks = 0; ks < 4; ++ks) {
                const int v = ks >> 1, k1 = ks & 1;
                union { u32 u[4]; f16x8 hv; } pa;
                pa.u[0] = s ? exv[v][k1][0] : loc[v][k1][0];
                pa.u[1] = s ? exv[v][k1][1] : loc[v][k1][1];
                pa.u[2] = s ? loc[v][k1][0] : exv[v][k1][0];
                pa.u[3] = s ? loc[v][k1][1] : exv[v][k1][1];
                const int tv = (ks * 2 + s) ^ (ql & 7);
                f16x8 vf0 = *(const f16x8*)((const char*)&KV[cur][1][0] + ql * 128 + tv * 16);
                f16x8 vf1 = *(const f16x8*)((const char*)&KV[cur][1][0] + (32 + ql) * 128 + tv * 16);
                oacc[0] = __builtin_amdgcn_mfma_f32_32x32x16_f16(pa.hv, vf0, oacc[0], 0, 0, 0);
                oacc[1] = __builtin_amdgcn_mfma_f32_32x32x16_f16(pa.hv, vf1, oacc[1], 0, 0, 0);
            }
        }
        asm volatile("s_waitcnt lgkmcnt(0)" ::: "memory");
        __builtin_amdgcn_sched_barrier(0);
        __builtin_amdgcn_s_barrier();
        __builtin_amdgcn_sched_barrier(0);
    }

    // ---- epilogue: normalize, transpose via LDS (reuse KV), coalesced store ----
    f16* Es = ((f16*)&KV[0][0][0]) + w * 2304;      // 32 rows x 72 f16 per wave
    const float linv = 1.0f / lrow;
#pragma unroll
    for (int r = 0; r < 16; ++r) {
        const int qr = (r & 3) + 8 * (r >> 2) + 4 * s;
        const float lb = __shfl(linv, qr);
        Es[qr * 72 + ql]      = (f16)(oacc[0][r] * lb);
        Es[qr * 72 + 32 + ql] = (f16)(oacc[1][r] * lb);
    }
    const int orow = lane >> 1;
    const int oh   = (lane & 1) * 32;
    const f16* srcp = ((const f16*)&KV[0][0][0]) + w * 2304 + orow * 72 + oh;
    f16* dst = Ob + (tokB + q0 + w * 32 + orow) * DM + h * 64 + oh;
#pragma unroll
    for (int t = 0; t < 4; ++t)
        *(f16x8*)(dst + t * 8) = *(const f16x8*)(srcp + t * 8);
}

// ---------------------------------------------------------------------------
// fused residual-add + LayerNorm
// ---------------------------------------------------------------------------
__global__ __launch_bounds__(256) void ln_k(
    long inOff, const float* __restrict__ residExt, long residOff,
    const float* __restrict__ gamma, const float* __restrict__ beta,
    float* __restrict__ outFExt, long outFOff, long outHOff)
{
    const float* in    = (const float*)(g_buf + inOff);
    const float* resid = residExt ? residExt : (const float*)(g_buf + residOff);
    float* outF = outFExt ? outFExt : (float*)(g_buf + outFOff);
    f16*  outH = (f16*)(g_buf + outHOff);

    const long row = blockIdx.x;
    const int tid = threadIdx.x;
    const int lane = tid & 63, wid = tid >> 6;

    float4 a  = ((const float4*)(in    + row * DM))[tid];
    float4 rr = ((const float4*)(resid + row * DM))[tid];
    float x0 = a.x + rr.x, x1 = a.y + rr.y, x2 = a.z + rr.z, x3 = a.w + rr.w;

    __shared__ float red[4];
    float ss = x0 + x1 + x2 + x3;
#pragma unroll
    for (int o = 32; o > 0; o >>= 1) ss += __shfl_xor(ss, o);
    if (lane == 0) red[wid] = ss;
    __syncthreads();
    const float mu = (red[0] + red[1] + red[2] + red[3]) * (1.0f / DM);

    float d0 = x0 - mu, d1 = x1 - mu, d2 = x2 - mu, d3 = x3 - mu;
    float qq = d0*d0 + d1*d1 + d2*d2 + d3*d3;
#pragma unroll
    for (int o = 32; o > 0; o >>= 1) qq += __shfl_xor(qq, o);
    __syncthreads();
    if (lane == 0) red[wid] = qq;
    __syncthreads();
    const float var = (red[0] + red[1] + red[2] + red[3]) * (1.0f / DM);
    const float rs = rsqrtf(var + 1e-6f);

    float4 g  = ((const float4*)gamma)[tid];
    float4 be = ((const float4*)beta)[tid];
    float y0 = d0 * rs * g.x + be.x;
    float y1 = d1 * rs * g.y + be.y;
    float y2 = d2 * rs * g.z + be.z;
    float y3 = d3 * rs * g.w + be.w;

    ((float4*)(outF + row * DM))[tid] = make_float4(y0, y1, y2, y3);
    f16x4 hh; hh.x = (f16)y0; hh.y = (f16)y1; hh.z = (f16)y2; hh.w = (f16)y3;
    *(f16x4*)(outH + row * DM + tid * 4) = hh;
}

// ---------------------------------------------------------------------------
extern "C" void kernel_launch(void* const* d_in, const int* in_sizes, int n_in,
                              void* d_out, int out_size, void* d_ws, size_t ws_size,
                              hipStream_t stream)
{
    (void)in_sizes; (void)n_in; (void)d_ws; (void)ws_size; (void)out_size;
    const float* x   = (const float*)d_in[0];
    const float* enc = (const float*)d_in[1];
    const float* wq1 = (const float*)d_in[2];  const float* bq1 = (const float*)d_in[3];
    const float* wk1 = (const float*)d_in[4];  const float* bk1 = (const float*)d_in[5];
    const float* wv1 = (const float*)d_in[6];  const float* bv1 = (const float*)d_in[7];
    const float* wo1 = (const float*)d_in[8];  const float* bo1 = (const float*)d_in[9];
    const float* wq2 = (const float*)d_in[10]; const float* bq2 = (const float*)d_in[11];
    const float* wk2 = (const float*)d_in[12]; const float* bk2 = (const float*)d_in[13];
    const float* wv2 = (const float*)d_in[14]; const float* bv2 = (const float*)d_in[15];
    const float* wo2 = (const float*)d_in[16]; const float* bo2 = (const float*)d_in[17];
    const float* wf1 = (const float*)d_in[18]; const float* bf1 = (const float*)d_in[19];
    const float* wf2 = (const float*)d_in[20]; const float* bf2 = (const float*)d_in[21];
    const float* g1  = (const float*)d_in[22]; const float* be1 = (const float*)d_in[23];
    const float* g2  = (const float*)d_in[24]; const float* be2 = (const float*)d_in[25];
    const float* g3  = (const float*)d_in[26]; const float* be3 = (const float*)d_in[27];
    float* out = (float*)d_out;

    const dim3 T256(256), T32x8(32, 8);

    // ---- converts & weight transposes ----
    cvt_f32_f16_k<<<8192, T256, 0, stream>>>(x,   OFF_XB);
    cvt_f32_f16_k<<<8192, T256, 0, stream>>>(enc, OFF_ENC);
    transw_k<<<dim3(32, 32),  T32x8, 0, stream>>>(wq1, WQ1T, 1024, 1024);
    transw_k<<<dim3(32, 32),  T32x8, 0, stream>>>(wk1, WK1T, 1024, 1024);
    transw_k<<<dim3(32, 32),  T32x8, 0, stream>>>(wv1, WV1T, 1024, 1024);
    transw_k<<<dim3(32, 32),  T32x8, 0, stream>>>(wo1, WO1T, 1024, 1024);
    transw_k<<<dim3(32, 32),  T32x8, 0, stream>>>(wq2, WQ2T, 1024, 1024);
    transw_k<<<dim3(32, 32),  T32x8, 0, stream>>>(wk2, WK2T, 1024, 1024);
    transw_k<<<dim3(32, 32),  T32x8, 0, stream>>>(wv2, WV2T, 1024, 1024);
    transw_k<<<dim3(32, 32),  T32x8, 0, stream>>>(wo2, WO2T, 1024, 1024);
    transw_k<<<dim3(128, 32), T32x8, 0, stream>>>(wf1, WF1T, 1024, 4096);
    transw_k<<<dim3(32, 128), T32x8, 0, stream>>>(wf2, WF2T, 4096, 1024);

    // ---- masked self-attention ----
    gemm_k<128,128,0><<<dim3(8,64), T256, 0, stream>>>(OFF_XB, WQ1T, OFF_Q, bq1, 1024, 1024,1024,1024);
    gemm_k<128,128,0><<<dim3(8,64), T256, 0, stream>>>(OFF_XB, WK1T, OFF_K, bk1, 1024, 1024,1024,1024);
    gemm_k<128,128,0><<<dim3(8,64), T256, 0, stream>>>(OFF_XB, WV1T, OFF_V, bv1, 1024, 1024,1024,1024);
    transv_k<<<dim3(64,2,64), T32x8, 0, stream>>>(OFF_V, OFF_VT);
    flash_k<1><<<dim3(16,64), T256, 0, stream>>>(OFF_Q, OFF_K, OFF_VT, OFF_AC);
    gemm_k<128,128,2><<<dim3(8,64), T256, 0, stream>>>(OFF_AC, WO1T, OFF_F2, bo1, 1024, 1024,1024,1024);
    ln_k<<<8192, T256, 0, stream>>>(OFF_F2, x, 0, g1, be1, nullptr, OFF_F1, OFF_XB);

    // ---- cross-attention (q=enc, k=enc, v=x1) ----
    gemm_k<128,128,0><<<dim3(8,64), T256, 0, stream>>>(OFF_ENC, WQ2T, OFF_Q, bq2, 1024, 1024,1024,1024);
    gemm_k<128,128,0><<<dim3(8,64), T256, 0, stream>>>(OFF_ENC, WK2T, OFF_K, bk2, 1024, 1024,1024,1024);
    gemm_k<128,128,0><<<dim3(8,64), T256, 0, stream>>>(OFF_XB, WV2T, OFF_V, bv2, 1024, 1024,1024,1024);
    transv_k<<<dim3(64,2,64), T32x8, 0, stream>>>(OFF_V, OFF_VT);
    flash_k<0><<<dim3(16,64), T256, 0, stream>>>(OFF_Q, OFF_K, OFF_VT, OFF_AC);
    gemm_k<128,128,2><<<dim3(8,64), T256, 0, stream>>>(OFF_AC, WO2T, OFF_F2, bo2, 1024, 1024,1024,1024);
    ln_k<<<8192, T256, 0, stream>>>(OFF_F2, nullptr, OFF_F1, g2, be2, nullptr, OFF_F3, OFF_XB);

    // ---- feed-forward ----
    gemm_k<128,128,1><<<dim3(32,64), T256, 0, stream>>>(OFF_XB, WF1T, OFF_HID, bf1, 1024, 1024,1024,4096);
    gemm_k<128,128,2><<<dim3(8,64), T256, 0, stream>>>(OFF_HID, WF2T, OFF_F2, bf2, 4096, 4096,4096,1024);
    ln_k<<<8192, T256, 0, stream>>>(OFF_F2, nullptr, OFF_F3, g3, be3, out, 0, OFF_XB);
}